// Round 9
// baseline (436.561 us; speedup 1.0000x reference)
//
#include <hip/hip_runtime.h>
#include <hip/hip_bf16.h>

typedef __hip_bfloat16 bf16;
typedef unsigned short u16;
typedef unsigned int u32;
typedef __attribute__((ext_vector_type(8))) short short8;
typedef __attribute__((ext_vector_type(4))) short bh4;
typedef __attribute__((ext_vector_type(4))) float floatx4;

constexpr int N_ = 2, H_ = 96, W_ = 96, HW_ = H_ * W_;
constexpr int CIN_ = 256, CH_ = 64, C2_ = 128;

__device__ __forceinline__ float sigm(float v) { return 1.0f / (1.0f + __expf(-v)); }
__device__ __forceinline__ short f2b(float v) { bf16 h = __float2bfloat16(v); return *reinterpret_cast<short*>(&h); }
__device__ __forceinline__ float b2f(short s) {
    union { u32 i; float f; } v; v.i = ((u32)(u16)s) << 16; return v.f;
}

// ---------- bf16 weight regions inside d_ws ----------
constexpr int A_IN_OFF = 0,                         A_IN_SZ  = 64 * 2304;
constexpr int A_OUT_OFF = A_IN_OFF + A_IN_SZ,       A_OUT_SZ = 256 * 576;
constexpr int A_OFF_OFF = A_OUT_OFF + A_OUT_SZ,     A_OFF_SZ = 64 * 1152;   // 27 padded to 64
constexpr int A_DCN_OFF = A_OFF_OFF + 4 * A_OFF_SZ, A_DCN_SZ = 64 * 1152;
constexpr int A_TOT = A_DCN_OFF + 4 * A_DCN_SZ;     // 884736 shorts = 1.77 MB
constexpr int CVT_BLKS = A_TOT / 256;               // 3456
constexpr int PREP_BLKS = 2880;

// ---------- fat: weight convert + input prep in one launch ----------
__global__ __launch_bounds__(256) void wprep(
        const float* __restrict__ w_in, const float* __restrict__ w_out,
        const float* __restrict__ ow0, const float* __restrict__ ow1,
        const float* __restrict__ ow2, const float* __restrict__ ow3,
        const float* __restrict__ w0, const float* __restrict__ w1,
        const float* __restrict__ w2, const float* __restrict__ w3,
        u16* __restrict__ dst,
        const float* __restrict__ x, const float* __restrict__ tpl,
        u16* __restrict__ xT, u16* __restrict__ ta, u16* __restrict__ tb) {
    if (blockIdx.x < CVT_BLKS) {
        int id = blockIdx.x * 256 + threadIdx.x;
        float v;
        if (id < A_OUT_OFF) {
            int l = id; int m = l / 2304, k = l % 2304; int tap = k >> 8, ic = k & 255;
            v = w_in[m * 2304 + ic * 9 + tap];
        } else if (id < A_OFF_OFF) {
            int l = id - A_OUT_OFF; int m = l / 576, k = l % 576; int tap = k / 64, ic = k & 63;
            v = w_out[m * 576 + ic * 9 + tap];
        } else if (id < A_DCN_OFF) {
            int l = id - A_OFF_OFF; int i = l / A_OFF_SZ, l2 = l % A_OFF_SZ;
            int m = l2 / 1152, k = l2 % 1152; int tap = k >> 7, ic = k & 127;
            const float* s = (i == 0) ? ow0 : (i == 1) ? ow1 : (i == 2) ? ow2 : ow3;
            v = (m < 27) ? s[m * 1152 + ic * 9 + tap] : 0.f;
        } else {
            int l = id - A_DCN_OFF; int i = l / A_DCN_SZ, l2 = l % A_DCN_SZ;
            int m = l2 / 1152, k = l2 % 1152; int tap = k >> 7, c = k & 127;
            const float* s = (i == 0) ? w0 : (i == 1) ? w1 : (i == 2) ? w2 : w3;
            v = s[m * 1152 + c * 9 + tap];
        }
        short sb = f2b(v);
        dst[id] = *reinterpret_cast<u16*>(&sb);
    } else {
        int id = (blockIdx.x - CVT_BLKS) * 256 + threadIdx.x;
        constexpr int XIDS = N_ * HW_ * 32;
        if (id < XIDS) {
            int c8 = id & 31;
            int pix = id >> 5;
            int n = pix / HW_, p = pix % HW_;
            const float* s = x + ((size_t)n * 256 + c8 * 8) * HW_ + p;
            short8 vv;
#pragma unroll
            for (int j = 0; j < 8; ++j) vv[j] = f2b(s[(size_t)j * HW_]);
            *reinterpret_cast<short8*>(xT + (size_t)pix * 256 + c8 * 8) = vv;
        } else {
            int id2 = id - XIDS;
            int c8 = id2 & 7;
            int pix = id2 >> 3;
            int n = pix / HW_, p = pix % HW_;
            const float* s = tpl + ((size_t)n * 64 + c8 * 8) * HW_ + p;
            short8 vv;
#pragma unroll
            for (int j = 0; j < 8; ++j) vv[j] = f2b(s[(size_t)j * HW_]);
            *reinterpret_cast<short8*>(ta + (size_t)pix * 128 + c8 * 8) = vv;
            *reinterpret_cast<short8*>(tb + (size_t)pix * 128 + 64 + c8 * 8) = vv;
        }
    }
}

// ---------- core implicit-GEMM body, 48-px strips; CC=1 adds concat epilogue ----------
template <int IC, int OCST, int CC>
__device__ __forceinline__ void conv_core(const u16* __restrict__ X,
                                          const u16* __restrict__ A,
                                          const float* __restrict__ bias,
                                          float* __restrict__ out,
                                          u16* __restrict__ ta, u16* __restrict__ tb,
                                          int r, int mt, int t) {
    constexpr int K = IC * 9;
    constexpr int ICC = IC / 64;
    __shared__ __align__(16) u16 Xl[3][50][72];
    int n = r / 192;
    int rr = r % 192;
    int y = rr >> 1, px0 = (rr & 1) * 48;
    int w = t >> 6, lane = t & 63, lm = lane & 15, q = lane >> 4;
    const u16* Arow = A + (size_t)(mt * 64 + w * 16 + lm) * K + q * 8;
    floatx4 acc[3];
#pragma unroll
    for (int a = 0; a < 3; ++a) acc[a] = {0.f, 0.f, 0.f, 0.f};
    const short8 zz = {0, 0, 0, 0, 0, 0, 0, 0};

    for (int icc = 0; icc < ICC; ++icc) {
        short8 af[9][2];
#pragma unroll
        for (int tap = 0; tap < 9; ++tap)
#pragma unroll
            for (int ks = 0; ks < 2; ++ks)
                af[tap][ks] = *reinterpret_cast<const short8*>(Arow + tap * IC + icc * 64 + ks * 32);
        __syncthreads();
#pragma unroll
        for (int it = 0; it < 5; ++it) {
            int id = it * 256 + t;
            if (id < 1200) {
                int ch8 = id & 7;
                int tmp = id >> 3;
                int pxl = tmp % 50, row = tmp / 50;
                int xg = px0 - 1 + pxl;
                int yg = y - 1 + row;
                bool vld = (yg >= 0) && (yg < 96) && (xg >= 0) && (xg < 96);
                short8 vv = zz;
                if (vld)
                    vv = *reinterpret_cast<const short8*>(
                        X + ((size_t)(n * HW_ + yg * 96 + xg)) * IC + icc * 64 + ch8 * 8);
                *reinterpret_cast<short8*>(&Xl[row][pxl][ch8 * 8]) = vv;
            }
        }
        __syncthreads();
#pragma unroll
        for (int tap = 0; tap < 9; ++tap) {
            int ky = tap / 3, kx = tap % 3;
#pragma unroll
            for (int ks = 0; ks < 2; ++ks) {
#pragma unroll
                for (int nf = 0; nf < 3; ++nf) {
                    short8 bv = *reinterpret_cast<const short8*>(&Xl[ky][nf * 16 + lm + kx][ks * 32 + q * 8]);
                    acc[nf] = __builtin_amdgcn_mfma_f32_16x16x32_bf16(af[tap][ks], bv, acc[nf], 0, 0, 0);
                }
            }
        }
    }
    int ocb = mt * 64 + w * 16 + q * 4;
#pragma unroll
    for (int nf = 0; nf < 3; ++nf) {
        int px = px0 + nf * 16 + lm;
        if constexpr (CC) {
            int pix = n * HW_ + y * 96 + px;
            bh4 bo;
#pragma unroll
            for (int rr2 = 0; rr2 < 4; ++rr2) {
                int oc = ocb + rr2;
                float v = acc[nf][rr2] + bias[oc];
                out[((size_t)(n * OCST + oc)) * HW_ + y * 96 + px] = v;
                bo[rr2] = f2b(v);
            }
            *reinterpret_cast<bh4*>(ta + (size_t)pix * 128 + 64 + ocb) = bo;   // xh -> ta ch 64..127
            *reinterpret_cast<bh4*>(tb + (size_t)pix * 128 + ocb) = bo;        // xh -> tb ch 0..63
        } else {
#pragma unroll
            for (int rr2 = 0; rr2 < 4; ++rr2) {
                int oc = ocb + rr2;
                if (oc < OCST)
                    out[((size_t)(n * OCST + oc)) * HW_ + y * 96 + px] = acc[nf][rr2] + bias[oc];
            }
        }
    }
}

template <int IC, int OCST, int CC>
__global__ __launch_bounds__(256) void conv_gemm(const u16* __restrict__ X,
                                                 const u16* __restrict__ A,
                                                 const float* __restrict__ bias,
                                                 float* __restrict__ out,
                                                 u16* __restrict__ ta, u16* __restrict__ tb) {
    int cpx = gridDim.x >> 3;
    int b = (blockIdx.x & 7) * cpx + (blockIdx.x >> 3);
    conv_core<IC, OCST, CC>(X, A, bias, out, ta, tb, b % 384, b / 384, threadIdx.x);
}

// ---------- wave-autonomous od: 16-px strip per wave, ZERO barriers ----------
// Wave owns px0..px0+15. Phase 1: private 18-px-halo offset conv (LDS slice, same-wave
// ordering only). Phase 2: per tap, lane(lm,q) bilinears 4 ch8-groups {q,q+4,q+8,q+12}
// of pixel px0+lm -> these ARE the 4 MFMA B-fragments (ch-slice ks has ch8=ks*4+q).
// B never touches LDS; no __syncthreads anywhere. Accumulation order per output elem
// unchanged (icc/tap/ks for phase 1; tap-major ch-slices 0..3 for phase 2) -> bit-identical.
// Wave LDS slice: Xl[3][18][72] u16 = 7776 B; om_l[27][16] f32 at 7776 (total 9504);
// tables (144*5*4=2880 B) overlay Xl after phase 1.
constexpr int ODW_B = 9504;
constexpr int SM_FAT = 4 * ODW_B;    // 38016 >= ncf's 33856

template <int GATE>
__device__ __forceinline__ void od_wave(char* lds, int strip, int lane,
        const u16* __restrict__ X0, const u16* __restrict__ X1,
        const u16* __restrict__ Ao0, const u16* __restrict__ Ao1,
        const float* __restrict__ bo0, const float* __restrict__ bo1,
        const u16* __restrict__ Ad0, const u16* __restrict__ Ad1,
        const float* __restrict__ bd0, const float* __restrict__ bd1,
        float* __restrict__ o0, float* __restrict__ o1,
        const float* __restrict__ g0, const float* __restrict__ g1,
        const float* __restrict__ t0, const float* __restrict__ t1,
        u16* __restrict__ xeh, float* __restrict__ ontpl) {
    u16 (*Xl)[18][72] = reinterpret_cast<u16(*)[18][72]>(lds);
    float (*om_l)[16] = reinterpret_cast<float(*)[16]>(lds + 7776);
    int* s_y0 = reinterpret_cast<int*>(lds);             // overlays Xl after phase 1
    int* s_x0 = s_y0 + 144;
    float* s_wy = reinterpret_cast<float*>(s_x0 + 144);
    float* s_wx = s_wy + 144;
    float* s_m  = s_wx + 144;                            // ends at 2880 < 7776

    int inst = strip / 1152, rem = strip % 1152;
    int n = rem / 576, rr = rem % 576;
    int y = rr / 6, px0 = (rr % 6) * 16;
    const u16* X = inst ? X1 : X0;
    const u16* Ao = inst ? Ao1 : Ao0;
    const float* bo = inst ? bo1 : bo0;
    const u16* Ad = inst ? Ad1 : Ad0;
    const float* bd = inst ? bd1 : bd0;
    int lm = lane & 15, q = lane >> 4;
    const short8 zz = {0, 0, 0, 0, 0, 0, 0, 0};

    // ---- phase 1: offset conv for 16 px (M=27, only mt 0..1 carry real weights) ----
    floatx4 accO[2];
    accO[0] = {0.f, 0.f, 0.f, 0.f};
    accO[1] = {0.f, 0.f, 0.f, 0.f};
    for (int icc = 0; icc < 2; ++icc) {
        for (int id = lane; id < 432; id += 64) {        // 3 rows x 18 px x 8 ch8
            int ch8 = id & 7;
            int tmp = id >> 3;
            int pxl = tmp % 18, row = tmp / 18;
            int xg = px0 - 1 + pxl, yg = y - 1 + row;
            short8 vv = zz;
            if (yg >= 0 && yg < 96 && xg >= 0 && xg < 96)
                vv = *reinterpret_cast<const short8*>(
                    X + ((size_t)(n * HW_ + yg * 96 + xg)) * 128 + icc * 64 + ch8 * 8);
            *reinterpret_cast<short8*>(&Xl[row][pxl][ch8 * 8]) = vv;
        }
#pragma unroll
        for (int tap = 0; tap < 9; ++tap) {
            int ky = tap / 3, kx = tap % 3;
#pragma unroll
            for (int ks = 0; ks < 2; ++ks) {
                short8 bv = *reinterpret_cast<const short8*>(&Xl[ky][lm + kx][ks * 32 + q * 8]);
#pragma unroll
                for (int mt = 0; mt < 2; ++mt) {
                    short8 af = *reinterpret_cast<const short8*>(
                        Ao + (size_t)(mt * 16 + lm) * 1152 + tap * 128 + icc * 64 + ks * 32 + q * 8);
                    accO[mt] = __builtin_amdgcn_mfma_f32_16x16x32_bf16(af, bv, accO[mt], 0, 0, 0);
                }
            }
        }
    }
#pragma unroll
    for (int mt = 0; mt < 2; ++mt)
#pragma unroll
        for (int rr2 = 0; rr2 < 4; ++rr2) {
            int oc = mt * 16 + q * 4 + rr2;
            if (oc < 27) om_l[oc][lm] = accO[mt][rr2] + bo[oc];
        }

    // ---- tables (16 px x 9 taps), overlaying dead Xl; om_l still live above ----
    for (int e = lane; e < 144; e += 64) {
        int k9 = e >> 4, xl = e & 15;
        int x = px0 + xl;
        float dy = om_l[k9][xl];
        float dx = om_l[9 + k9][xl];
        float ml = om_l[18 + k9][xl];
        float py = (float)y + (float)(k9 / 3 - 1) + dy;
        float px = (float)x + (float)(k9 % 3 - 1) + dx;
        float fy = floorf(py), fx = floorf(px);
        s_y0[e] = (int)fy; s_x0[e] = (int)fx;
        s_wy[e] = py - fy; s_wx[e] = px - fx; s_m[e] = sigm(ml);
    }

    // ---- phase 2: dcn, B-panel entirely in registers ----
    floatx4 acc[4];
#pragma unroll
    for (int a = 0; a < 4; ++a) acc[a] = {0.f, 0.f, 0.f, 0.f};
    const u16* txn = X + (size_t)n * HW_ * 128;
    for (int tap = 0; tap < 9; ++tap) {
        int ce = tap * 16 + lm;
        int y0 = s_y0[ce], x0c = s_x0[ce];
        float wy = s_wy[ce], wx = s_wx[ce], m = s_m[ce];
        float w00 = (1.f - wy) * (1.f - wx) * m;
        float w01 = (1.f - wy) * wx * m;
        float w10 = wy * (1.f - wx) * m;
        float w11 = wy * wx * m;
        bool yv0 = (y0 >= 0) & (y0 < 96), yv1 = (y0 >= -1) & (y0 < 95);
        bool xv0 = (x0c >= 0) & (x0c < 96), xv1 = (x0c >= -1) & (x0c < 95);
        const u16* gb = txn + (long)(y0 * 96 + x0c) * 128 + q * 8;
        short8 bf[4];
#pragma unroll
        for (int half = 0; half < 2; ++half) {
            short8 c[2][4];
#pragma unroll
            for (int it = 0; it < 2; ++it) {
                int choff = (half * 2 + it) * 32;
                c[it][0] = (yv0 && xv0) ? *reinterpret_cast<const short8*>(gb + choff) : zz;
                c[it][1] = (yv0 && xv1) ? *reinterpret_cast<const short8*>(gb + choff + 128) : zz;
                c[it][2] = (yv1 && xv0) ? *reinterpret_cast<const short8*>(gb + choff + 96 * 128) : zz;
                c[it][3] = (yv1 && xv1) ? *reinterpret_cast<const short8*>(gb + choff + 96 * 128 + 128) : zz;
            }
#pragma unroll
            for (int it = 0; it < 2; ++it) {
                short8 vv;
#pragma unroll
                for (int j = 0; j < 8; ++j) {
                    float f = b2f(c[it][0][j]) * w00 + b2f(c[it][1][j]) * w01 +
                              b2f(c[it][2][j]) * w10 + b2f(c[it][3][j]) * w11;
                    vv[j] = f2b(f);
                }
                bf[half * 2 + it] = vv;
            }
        }
#pragma unroll
        for (int ks = 0; ks < 4; ++ks)
#pragma unroll
            for (int mt = 0; mt < 4; ++mt) {
                short8 af = *reinterpret_cast<const short8*>(
                    Ad + (size_t)(mt * 16 + lm) * 1152 + tap * 128 + ks * 32 + q * 8);
                acc[mt] = __builtin_amdgcn_mfma_f32_16x16x32_bf16(af, bf[ks], acc[mt], 0, 0, 0);
            }
    }

    // ---- epilogue ----
    int px = px0 + lm;
    if constexpr (GATE == 0) {
        float* out = inst ? o1 : o0;
#pragma unroll
        for (int mt = 0; mt < 4; ++mt)
#pragma unroll
            for (int rr2 = 0; rr2 < 4; ++rr2) {
                int oc = mt * 16 + q * 4 + rr2;
                out[((size_t)(n * CH_ + oc)) * HW_ + y * 96 + px] = acc[mt][rr2] + bd[oc];
            }
    } else {
        const float* gz = inst ? g1 : g0;
        const float* tt = inst ? t1 : t0;
        if (!inst) {
#pragma unroll
            for (int mt = 0; mt < 4; ++mt) {
                bh4 bo4;
#pragma unroll
                for (int rr2 = 0; rr2 < 4; ++rr2) {
                    int oc = mt * 16 + q * 4 + rr2;
                    size_t idx = ((size_t)(n * CH_ + oc)) * HW_ + y * 96 + px;
                    float z = sigm(gz[idx]);
                    float xt = tanhf(acc[mt][rr2] + bd[oc]);
                    bo4[rr2] = f2b((1.f - z) * tt[idx] + z * xt);
                }
                *reinterpret_cast<bh4*>(xeh + ((size_t)(n * HW_ + y * 96 + px)) * 64 + mt * 16 + q * 4) = bo4;
            }
        } else {
#pragma unroll
            for (int mt = 0; mt < 4; ++mt)
#pragma unroll
                for (int rr2 = 0; rr2 < 4; ++rr2) {
                    int oc = mt * 16 + q * 4 + rr2;
                    size_t idx = ((size_t)(n * CH_ + oc)) * HW_ + y * 96 + px;
                    float z = sigm(gz[idx]);
                    float xt = tanhf(acc[mt][rr2] + bd[oc]);
                    ontpl[idx] = (1.f - z) * tt[idx] + z * xt;
                }
        }
    }
}

// ---------- ncf body, pool-based LDS (33856 B <= SM_FAT) ----------
__device__ __forceinline__ void ncf_body(char* smem, int b, int t,
        const u16* __restrict__ in0, const u16* __restrict__ in1,
        u16* __restrict__ out0, u16* __restrict__ out1) {
    u16 (*sF2)[28][72] = reinterpret_cast<u16(*)[28][72]>(smem);           // 28224 B
    u16 (*sF1)[72] = reinterpret_cast<u16(*)[72]>(smem + 28224);           // 2304 B
    float (*sc)[52] = reinterpret_cast<float(*)[52]>(smem + 30528);        // 3328 B
    int inst = b / 1152, bb = b % 1152;
    const u16* txh = inst ? in1 : in0;
    u16* txh2 = inst ? out1 : out0;
    int n = bb / 576, rem = bb % 576;
    int y = rem / 6, x0 = (rem % 6) * 16;
    const u16* base = txh + (size_t)n * HW_ * 128;
    const short8 zz = {0, 0, 0, 0, 0, 0, 0, 0};

    for (int id = t; id < 1568; id += 256) {
        int ch8 = id & 7;
        int tmp = id >> 3;
        int px = tmp % 28, row = tmp / 28;
        int yy = y + row * 2 - 6;
        int xg = x0 - 6 + px;
        short8 vv = zz;
        if (yy >= 0 && yy < 96 && xg >= 0 && xg < 96)
            vv = *reinterpret_cast<const short8*>(base + (size_t)(yy * 96 + xg) * 128 + ch8 * 8);
        *reinterpret_cast<short8*>(&sF2[row][px][ch8 * 8]) = vv;
    }
    if (t < 128) {
        int ch8 = t & 7, lp0 = t >> 3;
        short8 vv = *reinterpret_cast<const short8*>(base + (size_t)(y * 96 + x0 + lp0) * 128 + 64 + ch8 * 8);
        *reinterpret_cast<short8*>(&sF1[lp0][ch8 * 8]) = vv;
    }
    __syncthreads();

    int lp = t >> 4, j = t & 15;
    for (int k = j; k < 49; k += 16) {
        int ky = k / 7, kx = k % 7;
        const u16* f2p = &sF2[ky][lp + 2 * kx][0];
        const u16* f1p = &sF1[lp][0];
        float s = 0.f;
#pragma unroll
        for (int c8 = 0; c8 < 8; ++c8) {
            short8 a = *reinterpret_cast<const short8*>(f1p + c8 * 8);
            short8 b2 = *reinterpret_cast<const short8*>(f2p + c8 * 8);
#pragma unroll
            for (int u = 0; u < 8; ++u) s += b2f(a[u]) * b2f(b2[u]);
        }
        sc[lp][k] = s * 0.125f;
    }
    float mx = -1e30f;
    for (int k = j; k < 49; k += 16) mx = fmaxf(mx, sc[lp][k]);
#pragma unroll
    for (int m = 1; m <= 8; m <<= 1) mx = fmaxf(mx, __shfl_xor(mx, m, 64));
    float e[4];
    float sum = 0.f;
    int cnt = 0;
    for (int k = j; k < 49; k += 16) { e[cnt] = __expf(sc[lp][k] - mx); sum += e[cnt]; ++cnt; }
#pragma unroll
    for (int m = 1; m <= 8; m <<= 1) sum += __shfl_xor(sum, m, 64);
    float inv = 1.f / sum;
    cnt = 0;
    for (int k = j; k < 49; k += 16) sc[lp][k] = e[cnt++] * inv;
    __syncthreads();
    int ch0 = j * 4;
    float acc[4];
#pragma unroll
    for (int u = 0; u < 4; ++u) acc[u] = 0.f;
#pragma unroll
    for (int k = 0; k < 49; ++k) {
        int ky = k / 7, kx = k % 7;
        float a = sc[lp][k];
        bh4 f2 = *reinterpret_cast<const bh4*>(&sF2[ky][lp + 2 * kx][ch0]);
#pragma unroll
        for (int u = 0; u < 4; ++u) acc[u] += a * b2f(f2[u]);
    }
    int p = y * 96 + x0 + lp;
    u16* obase = txh2 + (size_t)n * HW_ * 128 + (size_t)p * 128;
    bh4 ro;
#pragma unroll
    for (int u = 0; u < 4; ++u) ro[u] = f2b(acc[u]);
    *reinterpret_cast<bh4*>(obase + ch0) = ro;
    *reinterpret_cast<bh4*>(obase + 64 + ch0) =
        *reinterpret_cast<const bh4*>(&sF1[lp][ch0]);   // tt passthrough
}

// ---------- fat: od<0> (576 blocks x 4 wave-strips) + ncf2 (2304 blocks) ----------
__global__ __launch_bounds__(256, 4) void od0_ncf(
        const u16* __restrict__ Xa, const u16* __restrict__ Xb,
        const u16* __restrict__ Ao0, const u16* __restrict__ Ao1,
        const float* __restrict__ bo0, const float* __restrict__ bo1,
        const u16* __restrict__ Ad0, const u16* __restrict__ Ad1,
        const float* __restrict__ bd0, const float* __restrict__ bd1,
        float* __restrict__ dz0, float* __restrict__ dz1,
        u16* __restrict__ t2a, u16* __restrict__ t2b) {
    __shared__ __align__(16) char smem[SM_FAT];
    int t = threadIdx.x;
    if (blockIdx.x < 576) {
        int bid = blockIdx.x;
        int b = (bid & 7) * 72 + (bid >> 3);             // XCD swizzle over 576
        int wid = t >> 6, lane = t & 63;
        od_wave<0>(smem + wid * ODW_B, b * 4 + wid, lane, Xa, Xb, Ao0, Ao1, bo0, bo1,
                   Ad0, Ad1, bd0, bd1, dz0, dz1,
                   nullptr, nullptr, nullptr, nullptr, nullptr, nullptr);
    } else {
        int bid = blockIdx.x - 576;
        int b = (bid & 7) * 288 + (bid >> 3);
        ncf_body(smem, b, t, Xa, Xb, t2a, t2b);
    }
}

// ---------- standalone od<1> with gate epilogue: 576 blocks x 4 wave-strips ----------
__global__ __launch_bounds__(256, 4) void od_gate(
        const u16* __restrict__ Xa, const u16* __restrict__ Xb,
        const u16* __restrict__ Ao0, const u16* __restrict__ Ao1,
        const float* __restrict__ bo0, const float* __restrict__ bo1,
        const u16* __restrict__ Ad0, const u16* __restrict__ Ad1,
        const float* __restrict__ bd0, const float* __restrict__ bd1,
        const float* __restrict__ g0, const float* __restrict__ g1,
        const float* __restrict__ t0, const float* __restrict__ t1,
        u16* __restrict__ xeh, float* __restrict__ ontpl) {
    __shared__ __align__(16) char smem[SM_FAT];
    int bid = blockIdx.x;
    int b = (bid & 7) * 72 + (bid >> 3);
    int wid = threadIdx.x >> 6, lane = threadIdx.x & 63;
    od_wave<1>(smem + wid * ODW_B, b * 4 + wid, lane, Xa, Xb, Ao0, Ao1, bo0, bo1,
               Ad0, Ad1, bd0, bd1, nullptr, nullptr, g0, g1, t0, t1, xeh, ontpl);
}

extern "C" void kernel_launch(void* const* d_in, const int* in_sizes, int n_in,
                              void* d_out, int out_size, void* d_ws, size_t ws_size,
                              hipStream_t stream) {
    const float* x     = (const float*)d_in[0];
    const float* tpl   = (const float*)d_in[1];
    const float* w_in  = (const float*)d_in[2];
    const float* b_in  = (const float*)d_in[3];
    const float* w_out = (const float*)d_in[4];
    const float* b_out = (const float*)d_in[5];
    const float *pw[4], *pb[4], *pow_[4], *pob[4];
    for (int i = 0; i < 4; ++i) {           // 0=enh_z 1=enh_h 2=upd_z 3=upd_h
        pw[i]   = (const float*)d_in[6 + 4 * i];
        pb[i]   = (const float*)d_in[7 + 4 * i];
        pow_[i] = (const float*)d_in[8 + 4 * i];
        pob[i]  = (const float*)d_in[9 + 4 * i];
    }
    float* out_main = (float*)d_out;
    float* out_ntpl = out_main + (size_t)N_ * CIN_ * HW_;

    // ---- workspace ----
    u16* Aws = (u16*)d_ws;
    u16* xT     = Aws + A_TOT;                        // (N,96,96,256) bf16
    u16* txh_a  = xT + (size_t)N_ * HW_ * CIN_;       // (N,96,96,128) bf16
    u16* txh_b  = txh_a + (size_t)N_ * HW_ * C2_;
    u16* txh2_a = txh_b + (size_t)N_ * HW_ * C2_;
    u16* txh2_b = txh2_a + (size_t)N_ * HW_ * C2_;
    u16* xeh    = txh2_b + (size_t)N_ * HW_ * C2_;    // (N,96,96,64) bf16
    float* fws = (float*)(xeh + (size_t)N_ * HW_ * CH_);
    size_t off = 0;
    float* xh   = fws + off; off += (size_t)N_ * CH_ * HW_;
    float* dz_a = fws + off; off += (size_t)N_ * CH_ * HW_;
    float* dz_b = fws + off; off += (size_t)N_ * CH_ * HW_;

    wprep<<<CVT_BLKS + PREP_BLKS, 256, 0, stream>>>(
        w_in, w_out, pow_[0], pow_[1], pow_[2], pow_[3], pw[0], pw[1], pw[2], pw[3], Aws,
        x, tpl, xT, txh_a, txh_b);
    conv_gemm<CIN_, 64, 1><<<384, 256, 0, stream>>>(xT, Aws + A_IN_OFF, b_in, xh, txh_a, txh_b);

    od0_ncf<<<2880, 256, 0, stream>>>(txh_a, txh_b,
        Aws + A_OFF_OFF + 0 * A_OFF_SZ, Aws + A_OFF_OFF + 2 * A_OFF_SZ, pob[0], pob[2],
        Aws + A_DCN_OFF + 0 * A_DCN_SZ, Aws + A_DCN_OFF + 2 * A_DCN_SZ, pb[0], pb[2],
        dz_a, dz_b, txh2_a, txh2_b);

    od_gate<<<576, 256, 0, stream>>>(txh2_a, txh2_b,
        Aws + A_OFF_OFF + 1 * A_OFF_SZ, Aws + A_OFF_OFF + 3 * A_OFF_SZ, pob[1], pob[3],
        Aws + A_DCN_OFF + 1 * A_DCN_SZ, Aws + A_DCN_OFF + 3 * A_DCN_SZ, pb[1], pb[3],
        dz_a, dz_b, xh, tpl, xeh, out_ntpl);

    conv_gemm<CH_, 256, 0><<<1536, 256, 0, stream>>>(xeh, Aws + A_OUT_OFF, b_out, out_main, nullptr, nullptr);
}

// Round 10
// 303.896 us; speedup vs baseline: 1.4365x; 1.4365x over previous
//
#include <hip/hip_runtime.h>
#include <hip/hip_bf16.h>

typedef __hip_bfloat16 bf16;
typedef unsigned short u16;
typedef unsigned int u32;
typedef __attribute__((ext_vector_type(8))) short short8;
typedef __attribute__((ext_vector_type(4))) short bh4;
typedef __attribute__((ext_vector_type(4))) float floatx4;

constexpr int N_ = 2, H_ = 96, W_ = 96, HW_ = H_ * W_;
constexpr int CIN_ = 256, CH_ = 64, C2_ = 128;

__device__ __forceinline__ float sigm(float v) { return 1.0f / (1.0f + __expf(-v)); }
__device__ __forceinline__ short f2b(float v) { bf16 h = __float2bfloat16(v); return *reinterpret_cast<short*>(&h); }
__device__ __forceinline__ float b2f(short s) {
    union { u32 i; float f; } v; v.i = ((u32)(u16)s) << 16; return v.f;
}

// ---------- bf16 weight regions inside d_ws ----------
constexpr int A_IN_OFF = 0,                         A_IN_SZ  = 64 * 2304;
constexpr int A_OUT_OFF = A_IN_OFF + A_IN_SZ,       A_OUT_SZ = 256 * 576;
constexpr int A_OFF_OFF = A_OUT_OFF + A_OUT_SZ,     A_OFF_SZ = 64 * 1152;   // 27 padded to 64
constexpr int A_DCN_OFF = A_OFF_OFF + 4 * A_OFF_SZ, A_DCN_SZ = 64 * 1152;
constexpr int A_TOT = A_DCN_OFF + 4 * A_DCN_SZ;     // 884736 shorts = 1.77 MB
constexpr int CVT_BLKS = A_TOT / 256;               // 3456
constexpr int PREP_BLKS = 2880;

// ---------- fat: weight convert + input prep in one launch ----------
__global__ __launch_bounds__(256) void wprep(
        const float* __restrict__ w_in, const float* __restrict__ w_out,
        const float* __restrict__ ow0, const float* __restrict__ ow1,
        const float* __restrict__ ow2, const float* __restrict__ ow3,
        const float* __restrict__ w0, const float* __restrict__ w1,
        const float* __restrict__ w2, const float* __restrict__ w3,
        u16* __restrict__ dst,
        const float* __restrict__ x, const float* __restrict__ tpl,
        u16* __restrict__ xT, u16* __restrict__ ta, u16* __restrict__ tb) {
    if (blockIdx.x < CVT_BLKS) {
        int id = blockIdx.x * 256 + threadIdx.x;
        float v;
        if (id < A_OUT_OFF) {
            int l = id; int m = l / 2304, k = l % 2304; int tap = k >> 8, ic = k & 255;
            v = w_in[m * 2304 + ic * 9 + tap];
        } else if (id < A_OFF_OFF) {
            int l = id - A_OUT_OFF; int m = l / 576, k = l % 576; int tap = k / 64, ic = k & 63;
            v = w_out[m * 576 + ic * 9 + tap];
        } else if (id < A_DCN_OFF) {
            int l = id - A_OFF_OFF; int i = l / A_OFF_SZ, l2 = l % A_OFF_SZ;
            int m = l2 / 1152, k = l2 % 1152; int tap = k >> 7, ic = k & 127;
            const float* s = (i == 0) ? ow0 : (i == 1) ? ow1 : (i == 2) ? ow2 : ow3;
            v = (m < 27) ? s[m * 1152 + ic * 9 + tap] : 0.f;
        } else {
            int l = id - A_DCN_OFF; int i = l / A_DCN_SZ, l2 = l % A_DCN_SZ;
            int m = l2 / 1152, k = l2 % 1152; int tap = k >> 7, c = k & 127;
            const float* s = (i == 0) ? w0 : (i == 1) ? w1 : (i == 2) ? w2 : w3;
            v = s[m * 1152 + c * 9 + tap];
        }
        short sb = f2b(v);
        dst[id] = *reinterpret_cast<u16*>(&sb);
    } else {
        int id = (blockIdx.x - CVT_BLKS) * 256 + threadIdx.x;
        constexpr int XIDS = N_ * HW_ * 32;
        if (id < XIDS) {
            int c8 = id & 31;
            int pix = id >> 5;
            int n = pix / HW_, p = pix % HW_;
            const float* s = x + ((size_t)n * 256 + c8 * 8) * HW_ + p;
            short8 vv;
#pragma unroll
            for (int j = 0; j < 8; ++j) vv[j] = f2b(s[(size_t)j * HW_]);
            *reinterpret_cast<short8*>(xT + (size_t)pix * 256 + c8 * 8) = vv;
        } else {
            int id2 = id - XIDS;
            int c8 = id2 & 7;
            int pix = id2 >> 3;
            int n = pix / HW_, p = pix % HW_;
            const float* s = tpl + ((size_t)n * 64 + c8 * 8) * HW_ + p;
            short8 vv;
#pragma unroll
            for (int j = 0; j < 8; ++j) vv[j] = f2b(s[(size_t)j * HW_]);
            *reinterpret_cast<short8*>(ta + (size_t)pix * 128 + c8 * 8) = vv;
            *reinterpret_cast<short8*>(tb + (size_t)pix * 128 + 64 + c8 * 8) = vv;
        }
    }
}

// ---------- core implicit-GEMM body, 32-px strips (R5 variant, higher occupancy) ----------
// r in [0, 576): n = r/288, row = (r%288)/3, strip = (r%288)%3 -> px0 = strip*32
template <int IC, int OCST, int CC>
__device__ __forceinline__ void conv_core(const u16* __restrict__ X,
                                          const u16* __restrict__ A,
                                          const float* __restrict__ bias,
                                          float* __restrict__ out,
                                          u16* __restrict__ ta, u16* __restrict__ tb,
                                          int r, int mt, int t) {
    constexpr int K = IC * 9;
    constexpr int ICC = IC / 64;
    __shared__ __align__(16) u16 Xl[3][34][72];
    int n = r / 288;
    int rr = r % 288;
    int y = rr / 3, px0 = (rr % 3) * 32;
    int w = t >> 6, lane = t & 63, lm = lane & 15, q = lane >> 4;
    const u16* Arow = A + (size_t)(mt * 64 + w * 16 + lm) * K + q * 8;
    floatx4 acc[2];
#pragma unroll
    for (int a = 0; a < 2; ++a) acc[a] = {0.f, 0.f, 0.f, 0.f};
    const short8 zz = {0, 0, 0, 0, 0, 0, 0, 0};

    for (int icc = 0; icc < ICC; ++icc) {
        short8 af[9][2];
#pragma unroll
        for (int tap = 0; tap < 9; ++tap)
#pragma unroll
            for (int ks = 0; ks < 2; ++ks)
                af[tap][ks] = *reinterpret_cast<const short8*>(Arow + tap * IC + icc * 64 + ks * 32);
        __syncthreads();
#pragma unroll
        for (int it = 0; it < 4; ++it) {
            int id = it * 256 + t;
            if (id < 816) {                     // 3 rows x 34 cols x 8 ch8
                int ch8 = id & 7;
                int tmp = id >> 3;
                int pxl = tmp % 34, row = tmp / 34;
                int xg = px0 - 1 + pxl;
                int yg = y - 1 + row;
                bool vld = (yg >= 0) && (yg < 96) && (xg >= 0) && (xg < 96);
                short8 vv = zz;
                if (vld)
                    vv = *reinterpret_cast<const short8*>(
                        X + ((size_t)(n * HW_ + yg * 96 + xg)) * IC + icc * 64 + ch8 * 8);
                *reinterpret_cast<short8*>(&Xl[row][pxl][ch8 * 8]) = vv;
            }
        }
        __syncthreads();
#pragma unroll
        for (int tap = 0; tap < 9; ++tap) {
            int ky = tap / 3, kx = tap % 3;
#pragma unroll
            for (int ks = 0; ks < 2; ++ks) {
#pragma unroll
                for (int nf = 0; nf < 2; ++nf) {
                    short8 bv = *reinterpret_cast<const short8*>(&Xl[ky][nf * 16 + lm + kx][ks * 32 + q * 8]);
                    acc[nf] = __builtin_amdgcn_mfma_f32_16x16x32_bf16(af[tap][ks], bv, acc[nf], 0, 0, 0);
                }
            }
        }
    }
    int ocb = mt * 64 + w * 16 + q * 4;
#pragma unroll
    for (int nf = 0; nf < 2; ++nf) {
        int px = px0 + nf * 16 + lm;
        if constexpr (CC) {
            int pix = n * HW_ + y * 96 + px;
            bh4 bo;
#pragma unroll
            for (int rr2 = 0; rr2 < 4; ++rr2) {
                int oc = ocb + rr2;
                float v = acc[nf][rr2] + bias[oc];
                out[((size_t)(n * OCST + oc)) * HW_ + y * 96 + px] = v;
                bo[rr2] = f2b(v);
            }
            *reinterpret_cast<bh4*>(ta + (size_t)pix * 128 + 64 + ocb) = bo;   // xh -> ta ch 64..127
            *reinterpret_cast<bh4*>(tb + (size_t)pix * 128 + ocb) = bo;        // xh -> tb ch 0..63
        } else {
#pragma unroll
            for (int rr2 = 0; rr2 < 4; ++rr2) {
                int oc = ocb + rr2;
                if (oc < OCST)
                    out[((size_t)(n * OCST + oc)) * HW_ + y * 96 + px] = acc[nf][rr2] + bias[oc];
            }
        }
    }
}

template <int IC, int OCST, int CC>
__global__ __launch_bounds__(256) void conv_gemm(const u16* __restrict__ X,
                                                 const u16* __restrict__ A,
                                                 const float* __restrict__ bias,
                                                 float* __restrict__ out,
                                                 u16* __restrict__ ta, u16* __restrict__ tb) {
    // XCD-aware bijective swizzle (gridDim.x % 8 == 0)
    int cpx = gridDim.x >> 3;
    int b = (blockIdx.x & 7) * cpx + (blockIdx.x >> 3);
    conv_core<IC, OCST, CC>(X, A, bias, out, ta, tb, b % 576, b / 576, threadIdx.x);
}

// ---------- od body (offset-conv + dcn + optional gate), pool-based LDS (R7 proven) ----------
// 48-px strips. Phase 2 staged PER TAP: 9 barrier steps, 3 items/thread, 12 MFMAs/step.
// LDS pool (bytes): phase1 Xl[3][50][72]=21600 + om_l[27][48]=5184 -> 26784;
// phase2 Bl[2][48][136]=26112 overlays; tables at 26784: 432*5*4=8640; total 35424.
constexpr int P1XL_B = 21600;
constexpr int P1_B   = 26784;
constexpr int SM_SZ2 = 35424;

template <int GATE>
__device__ __forceinline__ void od_body(char* smem, int b, int t,
        const u16* __restrict__ X0, const u16* __restrict__ X1,
        const u16* __restrict__ Ao0, const u16* __restrict__ Ao1,
        const float* __restrict__ bo0, const float* __restrict__ bo1,
        const u16* __restrict__ Ad0, const u16* __restrict__ Ad1,
        const float* __restrict__ bd0, const float* __restrict__ bd1,
        float* __restrict__ o0, float* __restrict__ o1,
        const float* __restrict__ g0, const float* __restrict__ g1,
        const float* __restrict__ t0, const float* __restrict__ t1,
        u16* __restrict__ xeh, float* __restrict__ ontpl) {
    u16 (*Xl)[50][72] = reinterpret_cast<u16(*)[50][72]>(smem);
    float (*om_l)[48] = reinterpret_cast<float(*)[48]>(smem + P1XL_B);
    u16 (*Bl)[48][136] = reinterpret_cast<u16(*)[48][136]>(smem);
    int* s_y0 = reinterpret_cast<int*>(smem + P1_B);
    int* s_x0 = s_y0 + 432;
    float* s_wy = reinterpret_cast<float*>(s_x0 + 432);
    float* s_wx = s_wy + 432;
    float* s_m  = s_wx + 432;

    int inst = b / 384, r = b % 384;
    const u16* X = inst ? X1 : X0;
    const u16* Ao = inst ? Ao1 : Ao0;
    const float* bo = inst ? bo1 : bo0;
    const u16* Ad = inst ? Ad1 : Ad0;
    const float* bd = inst ? bd1 : bd0;
    int n = r / 192, rr = r % 192;
    int y = rr >> 1, px0 = (rr & 1) * 48;
    int w = t >> 6, lane = t & 63, lm = lane & 15, q = lane >> 4;
    const short8 zz = {0, 0, 0, 0, 0, 0, 0, 0};

    // ---- phase 1: offset conv -> om_l ----
    {
        const u16* Arow = Ao + (size_t)(w * 16 + lm) * 1152 + q * 8;
        floatx4 acc[3];
#pragma unroll
        for (int a = 0; a < 3; ++a) acc[a] = {0.f, 0.f, 0.f, 0.f};
        for (int icc = 0; icc < 2; ++icc) {
            short8 af[9][2];
#pragma unroll
            for (int tap = 0; tap < 9; ++tap)
#pragma unroll
                for (int ks = 0; ks < 2; ++ks)
                    af[tap][ks] = *reinterpret_cast<const short8*>(Arow + tap * 128 + icc * 64 + ks * 32);
            __syncthreads();
#pragma unroll
            for (int it = 0; it < 5; ++it) {
                int id = it * 256 + t;
                if (id < 1200) {
                    int ch8 = id & 7;
                    int tmp = id >> 3;
                    int pxl = tmp % 50, row = tmp / 50;
                    int xg = px0 - 1 + pxl;
                    int yg = y - 1 + row;
                    bool vld = (yg >= 0) && (yg < 96) && (xg >= 0) && (xg < 96);
                    short8 vv = zz;
                    if (vld)
                        vv = *reinterpret_cast<const short8*>(
                            X + ((size_t)(n * HW_ + yg * 96 + xg)) * 128 + icc * 64 + ch8 * 8);
                    *reinterpret_cast<short8*>(&Xl[row][pxl][ch8 * 8]) = vv;
                }
            }
            __syncthreads();
#pragma unroll
            for (int tap = 0; tap < 9; ++tap) {
                int ky = tap / 3, kx = tap % 3;
#pragma unroll
                for (int ks = 0; ks < 2; ++ks) {
#pragma unroll
                    for (int nf = 0; nf < 3; ++nf) {
                        short8 bv = *reinterpret_cast<const short8*>(&Xl[ky][nf * 16 + lm + kx][ks * 32 + q * 8]);
                        acc[nf] = __builtin_amdgcn_mfma_f32_16x16x32_bf16(af[tap][ks], bv, acc[nf], 0, 0, 0);
                    }
                }
            }
        }
        int ocb = w * 16 + q * 4;
#pragma unroll
        for (int nf = 0; nf < 3; ++nf) {
            int xl = nf * 16 + lm;
#pragma unroll
            for (int rr2 = 0; rr2 < 4; ++rr2) {
                int oc = ocb + rr2;
                if (oc < 27) om_l[oc][xl] = acc[nf][rr2] + bo[oc];
            }
        }
    }
    __syncthreads();

    for (int e = t; e < 432; e += 256) {
        int k9 = e / 48, xl = e % 48;
        int x = px0 + xl;
        float dy = om_l[k9][xl];
        float dx = om_l[9 + k9][xl];
        float ml = om_l[18 + k9][xl];
        float py = (float)y + (float)(k9 / 3 - 1) + dy;
        float px = (float)x + (float)(k9 % 3 - 1) + dx;
        float fy = floorf(py), fx = floorf(px);
        s_y0[e] = (int)fy; s_x0[e] = (int)fx;
        s_wy[e] = py - fy; s_wx[e] = px - fx; s_m[e] = sigm(ml);
    }
    __syncthreads();

    // ---- phase 2: dcn, per-tap staging, register-pipelined ----
    const u16* Arow = Ad + (size_t)(w * 16 + lm) * 1152 + q * 8;
    floatx4 acc[3];
#pragma unroll
    for (int a = 0; a < 3; ++a) acc[a] = {0.f, 0.f, 0.f, 0.f};
    const u16* txn = X + (size_t)n * HW_ * 128;
    int p = 0;
    int cg = t & 15, px0i = t >> 4;
    short8 cr[3][4];
    short8 afP[2][2];

    auto issueT = [&](int tap) {
#pragma unroll
        for (int s = 0; s < 3; ++s) {
            int pxi = px0i + s * 16;
            int ce = tap * 48 + pxi;
            int y0 = s_y0[ce], x0c = s_x0[ce];
            bool yv0 = (y0 >= 0) & (y0 < 96), yv1 = (y0 >= -1) & (y0 < 95);
            bool xv0 = (x0c >= 0) & (x0c < 96), xv1 = (x0c >= -1) & (x0c < 95);
            const u16* gb = txn + (long)(y0 * 96 + x0c) * 128 + cg * 8;
            cr[s][0] = (yv0 && xv0) ? *reinterpret_cast<const short8*>(gb) : zz;
            cr[s][1] = (yv0 && xv1) ? *reinterpret_cast<const short8*>(gb + 128) : zz;
            cr[s][2] = (yv1 && xv0) ? *reinterpret_cast<const short8*>(gb + 96 * 128) : zz;
            cr[s][3] = (yv1 && xv1) ? *reinterpret_cast<const short8*>(gb + 96 * 128 + 128) : zz;
        }
    };
    auto computeT = [&](int tap) {
#pragma unroll
        for (int s = 0; s < 3; ++s) {
            int pxi = px0i + s * 16;
            int ce = tap * 48 + pxi;
            float wy = s_wy[ce], wx = s_wx[ce], m = s_m[ce];
            float w00 = (1.f - wy) * (1.f - wx) * m;
            float w01 = (1.f - wy) * wx * m;
            float w10 = wy * (1.f - wx) * m;
            float w11 = wy * wx * m;
            short8 vv;
#pragma unroll
            for (int j = 0; j < 8; ++j) {
                float f = b2f(cr[s][0][j]) * w00 + b2f(cr[s][1][j]) * w01 +
                          b2f(cr[s][2][j]) * w10 + b2f(cr[s][3][j]) * w11;
                vv[j] = f2b(f);
            }
            *reinterpret_cast<short8*>(&Bl[p][pxi][cg * 8]) = vv;
        }
    };

    issueT(0);
    for (int tap = 0; tap < 9; ++tap) {
        if (tap > 0) {
#pragma unroll
            for (int half = 0; half < 2; ++half)
#pragma unroll
                for (int ks = 0; ks < 2; ++ks)
#pragma unroll
                    for (int nf = 0; nf < 3; ++nf) {
                        short8 bv = *reinterpret_cast<const short8*>(
                            &Bl[p ^ 1][nf * 16 + lm][half * 64 + ks * 32 + q * 8]);
                        acc[nf] = __builtin_amdgcn_mfma_f32_16x16x32_bf16(afP[half][ks], bv, acc[nf], 0, 0, 0);
                    }
        }
        computeT(tap);
        if (tap < 8) issueT(tap + 1);
#pragma unroll
        for (int half = 0; half < 2; ++half)
#pragma unroll
            for (int ks = 0; ks < 2; ++ks)
                afP[half][ks] = *reinterpret_cast<const short8*>(Arow + (tap * 2 + half) * 64 + ks * 32);
        __syncthreads();
        p ^= 1;
    }
#pragma unroll
    for (int half = 0; half < 2; ++half)
#pragma unroll
        for (int ks = 0; ks < 2; ++ks)
#pragma unroll
            for (int nf = 0; nf < 3; ++nf) {
                short8 bv = *reinterpret_cast<const short8*>(
                    &Bl[p ^ 1][nf * 16 + lm][half * 64 + ks * 32 + q * 8]);
                acc[nf] = __builtin_amdgcn_mfma_f32_16x16x32_bf16(afP[half][ks], bv, acc[nf], 0, 0, 0);
            }

    int ocb = w * 16 + q * 4;
    if constexpr (GATE == 0) {
        float* out = inst ? o1 : o0;
#pragma unroll
        for (int nf = 0; nf < 3; ++nf) {
            int px = px0 + nf * 16 + lm;
#pragma unroll
            for (int rr2 = 0; rr2 < 4; ++rr2) {
                int oc = ocb + rr2;
                out[((size_t)(n * CH_ + oc)) * HW_ + y * 96 + px] = acc[nf][rr2] + bd[oc];
            }
        }
    } else {
        const float* gz = inst ? g1 : g0;
        const float* tt = inst ? t1 : t0;
#pragma unroll
        for (int nf = 0; nf < 3; ++nf) {
            int px = px0 + nf * 16 + lm;
            if (!inst) {
                bh4 bo4;
#pragma unroll
                for (int rr2 = 0; rr2 < 4; ++rr2) {
                    int oc = ocb + rr2;
                    size_t idx = ((size_t)(n * CH_ + oc)) * HW_ + y * 96 + px;
                    float z = sigm(gz[idx]);
                    float xt = tanhf(acc[nf][rr2] + bd[oc]);
                    bo4[rr2] = f2b((1.f - z) * tt[idx] + z * xt);
                }
                *reinterpret_cast<bh4*>(xeh + ((size_t)(n * HW_ + y * 96 + px)) * 64 + ocb) = bo4;
            } else {
#pragma unroll
                for (int rr2 = 0; rr2 < 4; ++rr2) {
                    int oc = ocb + rr2;
                    size_t idx = ((size_t)(n * CH_ + oc)) * HW_ + y * 96 + px;
                    float z = sigm(gz[idx]);
                    float xt = tanhf(acc[nf][rr2] + bd[oc]);
                    ontpl[idx] = (1.f - z) * tt[idx] + z * xt;
                }
            }
        }
    }
}

// ---------- ncf body, pool-based LDS (33856 B <= SM_SZ2) ----------
__device__ __forceinline__ void ncf_body(char* smem, int b, int t,
        const u16* __restrict__ in0, const u16* __restrict__ in1,
        u16* __restrict__ out0, u16* __restrict__ out1) {
    u16 (*sF2)[28][72] = reinterpret_cast<u16(*)[28][72]>(smem);           // 28224 B
    u16 (*sF1)[72] = reinterpret_cast<u16(*)[72]>(smem + 28224);           // 2304 B
    float (*sc)[52] = reinterpret_cast<float(*)[52]>(smem + 30528);        // 3328 B
    int inst = b / 1152, bb = b % 1152;
    const u16* txh = inst ? in1 : in0;
    u16* txh2 = inst ? out1 : out0;
    int n = bb / 576, rem = bb % 576;
    int y = rem / 6, x0 = (rem % 6) * 16;
    const u16* base = txh + (size_t)n * HW_ * 128;
    const short8 zz = {0, 0, 0, 0, 0, 0, 0, 0};

    for (int id = t; id < 1568; id += 256) {
        int ch8 = id & 7;
        int tmp = id >> 3;
        int px = tmp % 28, row = tmp / 28;
        int yy = y + row * 2 - 6;
        int xg = x0 - 6 + px;
        short8 vv = zz;
        if (yy >= 0 && yy < 96 && xg >= 0 && xg < 96)
            vv = *reinterpret_cast<const short8*>(base + (size_t)(yy * 96 + xg) * 128 + ch8 * 8);
        *reinterpret_cast<short8*>(&sF2[row][px][ch8 * 8]) = vv;
    }
    if (t < 128) {
        int ch8 = t & 7, lp0 = t >> 3;
        short8 vv = *reinterpret_cast<const short8*>(base + (size_t)(y * 96 + x0 + lp0) * 128 + 64 + ch8 * 8);
        *reinterpret_cast<short8*>(&sF1[lp0][ch8 * 8]) = vv;
    }
    __syncthreads();

    int lp = t >> 4, j = t & 15;
    for (int k = j; k < 49; k += 16) {
        int ky = k / 7, kx = k % 7;
        const u16* f2p = &sF2[ky][lp + 2 * kx][0];
        const u16* f1p = &sF1[lp][0];
        float s = 0.f;
#pragma unroll
        for (int c8 = 0; c8 < 8; ++c8) {
            short8 a = *reinterpret_cast<const short8*>(f1p + c8 * 8);
            short8 b2 = *reinterpret_cast<const short8*>(f2p + c8 * 8);
#pragma unroll
            for (int u = 0; u < 8; ++u) s += b2f(a[u]) * b2f(b2[u]);
        }
        sc[lp][k] = s * 0.125f;
    }
    float mx = -1e30f;
    for (int k = j; k < 49; k += 16) mx = fmaxf(mx, sc[lp][k]);
#pragma unroll
    for (int m = 1; m <= 8; m <<= 1) mx = fmaxf(mx, __shfl_xor(mx, m, 64));
    float e[4];
    float sum = 0.f;
    int cnt = 0;
    for (int k = j; k < 49; k += 16) { e[cnt] = __expf(sc[lp][k] - mx); sum += e[cnt]; ++cnt; }
#pragma unroll
    for (int m = 1; m <= 8; m <<= 1) sum += __shfl_xor(sum, m, 64);
    float inv = 1.f / sum;
    cnt = 0;
    for (int k = j; k < 49; k += 16) sc[lp][k] = e[cnt++] * inv;
    __syncthreads();
    int ch0 = j * 4;
    float acc[4];
#pragma unroll
    for (int u = 0; u < 4; ++u) acc[u] = 0.f;
#pragma unroll
    for (int k = 0; k < 49; ++k) {
        int ky = k / 7, kx = k % 7;
        float a = sc[lp][k];
        bh4 f2 = *reinterpret_cast<const bh4*>(&sF2[ky][lp + 2 * kx][ch0]);
#pragma unroll
        for (int u = 0; u < 4; ++u) acc[u] += a * b2f(f2[u]);
    }
    int p = y * 96 + x0 + lp;
    u16* obase = txh2 + (size_t)n * HW_ * 128 + (size_t)p * 128;
    bh4 ro;
#pragma unroll
    for (int u = 0; u < 4; ++u) ro[u] = f2b(acc[u]);
    *reinterpret_cast<bh4*>(obase + ch0) = ro;
    *reinterpret_cast<bh4*>(obase + 64 + ch0) =
        *reinterpret_cast<const bh4*>(&sF1[lp][ch0]);   // tt passthrough
}

// ---------- fat: od<0> (768 blocks) + ncf2 (2304 blocks) co-resident ----------
__global__ __launch_bounds__(256, 4) void od0_ncf(
        const u16* __restrict__ Xa, const u16* __restrict__ Xb,
        const u16* __restrict__ Ao0, const u16* __restrict__ Ao1,
        const float* __restrict__ bo0, const float* __restrict__ bo1,
        const u16* __restrict__ Ad0, const u16* __restrict__ Ad1,
        const float* __restrict__ bd0, const float* __restrict__ bd1,
        float* __restrict__ dz0, float* __restrict__ dz1,
        u16* __restrict__ t2a, u16* __restrict__ t2b) {
    __shared__ __align__(16) char smem[SM_SZ2];
    int t = threadIdx.x;
    if (blockIdx.x < 768) {
        int bid = blockIdx.x;
        int b = (bid & 7) * 96 + (bid >> 3);
        od_body<0>(smem, b, t, Xa, Xb, Ao0, Ao1, bo0, bo1, Ad0, Ad1, bd0, bd1,
                   dz0, dz1, nullptr, nullptr, nullptr, nullptr, nullptr, nullptr);
    } else {
        int bid = blockIdx.x - 768;
        int b = (bid & 7) * 288 + (bid >> 3);
        ncf_body(smem, b, t, Xa, Xb, t2a, t2b);
    }
}

// ---------- standalone od<1> with gate epilogue ----------
__global__ __launch_bounds__(256, 4) void od_gate(
        const u16* __restrict__ Xa, const u16* __restrict__ Xb,
        const u16* __restrict__ Ao0, const u16* __restrict__ Ao1,
        const float* __restrict__ bo0, const float* __restrict__ bo1,
        const u16* __restrict__ Ad0, const u16* __restrict__ Ad1,
        const float* __restrict__ bd0, const float* __restrict__ bd1,
        const float* __restrict__ g0, const float* __restrict__ g1,
        const float* __restrict__ t0, const float* __restrict__ t1,
        u16* __restrict__ xeh, float* __restrict__ ontpl) {
    __shared__ __align__(16) char smem[SM_SZ2];
    int bid = blockIdx.x;
    int b = (bid & 7) * 96 + (bid >> 3);
    od_body<1>(smem, b, threadIdx.x, Xa, Xb, Ao0, Ao1, bo0, bo1, Ad0, Ad1, bd0, bd1,
               nullptr, nullptr, g0, g1, t0, t1, xeh, ontpl);
}

extern "C" void kernel_launch(void* const* d_in, const int* in_sizes, int n_in,
                              void* d_out, int out_size, void* d_ws, size_t ws_size,
                              hipStream_t stream) {
    const float* x     = (const float*)d_in[0];
    const float* tpl   = (const float*)d_in[1];
    const float* w_in  = (const float*)d_in[2];
    const float* b_in  = (const float*)d_in[3];
    const float* w_out = (const float*)d_in[4];
    const float* b_out = (const float*)d_in[5];
    const float *pw[4], *pb[4], *pow_[4], *pob[4];
    for (int i = 0; i < 4; ++i) {           // 0=enh_z 1=enh_h 2=upd_z 3=upd_h
        pw[i]   = (const float*)d_in[6 + 4 * i];
        pb[i]   = (const float*)d_in[7 + 4 * i];
        pow_[i] = (const float*)d_in[8 + 4 * i];
        pob[i]  = (const float*)d_in[9 + 4 * i];
    }
    float* out_main = (float*)d_out;
    float* out_ntpl = out_main + (size_t)N_ * CIN_ * HW_;

    // ---- workspace ----
    u16* Aws = (u16*)d_ws;
    u16* xT     = Aws + A_TOT;                        // (N,96,96,256) bf16
    u16* txh_a  = xT + (size_t)N_ * HW_ * CIN_;       // (N,96,96,128) bf16
    u16* txh_b  = txh_a + (size_t)N_ * HW_ * C2_;
    u16* txh2_a = txh_b + (size_t)N_ * HW_ * C2_;
    u16* txh2_b = txh2_a + (size_t)N_ * HW_ * C2_;
    u16* xeh    = txh2_b + (size_t)N_ * HW_ * C2_;    // (N,96,96,64) bf16
    float* fws = (float*)(xeh + (size_t)N_ * HW_ * CH_);
    size_t off = 0;
    float* xh   = fws + off; off += (size_t)N_ * CH_ * HW_;
    float* dz_a = fws + off; off += (size_t)N_ * CH_ * HW_;
    float* dz_b = fws + off; off += (size_t)N_ * CH_ * HW_;

    wprep<<<CVT_BLKS + PREP_BLKS, 256, 0, stream>>>(
        w_in, w_out, pow_[0], pow_[1], pow_[2], pow_[3], pw[0], pw[1], pw[2], pw[3], Aws,
        x, tpl, xT, txh_a, txh_b);
    conv_gemm<CIN_, 64, 1><<<576, 256, 0, stream>>>(xT, Aws + A_IN_OFF, b_in, xh, txh_a, txh_b);

    od0_ncf<<<3072, 256, 0, stream>>>(txh_a, txh_b,
        Aws + A_OFF_OFF + 0 * A_OFF_SZ, Aws + A_OFF_OFF + 2 * A_OFF_SZ, pob[0], pob[2],
        Aws + A_DCN_OFF + 0 * A_DCN_SZ, Aws + A_DCN_OFF + 2 * A_DCN_SZ, pb[0], pb[2],
        dz_a, dz_b, txh2_a, txh2_b);

    od_gate<<<768, 256, 0, stream>>>(txh2_a, txh2_b,
        Aws + A_OFF_OFF + 1 * A_OFF_SZ, Aws + A_OFF_OFF + 3 * A_OFF_SZ, pob[1], pob[3],
        Aws + A_DCN_OFF + 1 * A_DCN_SZ, Aws + A_DCN_OFF + 3 * A_DCN_SZ, pb[1], pb[3],
        dz_a, dz_b, xh, tpl, xeh, out_ntpl);

    conv_gemm<CH_, 256, 0><<<2304, 256, 0, stream>>>(xeh, Aws + A_OUT_OFF, b_out, out_main, nullptr, nullptr);
}

// Round 11
// 291.445 us; speedup vs baseline: 1.4979x; 1.0427x over previous
//
#include <hip/hip_runtime.h>
#include <hip/hip_bf16.h>

typedef __hip_bfloat16 bf16;
typedef unsigned short u16;
typedef unsigned int u32;
typedef __attribute__((ext_vector_type(8))) short short8;
typedef __attribute__((ext_vector_type(4))) short bh4;
typedef __attribute__((ext_vector_type(4))) float floatx4;

constexpr int N_ = 2, H_ = 96, W_ = 96, HW_ = H_ * W_;
constexpr int CIN_ = 256, CH_ = 64, C2_ = 128;

__device__ __forceinline__ float sigm(float v) { return 1.0f / (1.0f + __expf(-v)); }
__device__ __forceinline__ short f2b(float v) { bf16 h = __float2bfloat16(v); return *reinterpret_cast<short*>(&h); }
__device__ __forceinline__ float b2f(short s) {
    union { u32 i; float f; } v; v.i = ((u32)(u16)s) << 16; return v.f;
}

// ---------- bf16 weight regions inside d_ws ----------
constexpr int A_IN_OFF = 0,                         A_IN_SZ  = 64 * 2304;
constexpr int A_OUT_OFF = A_IN_OFF + A_IN_SZ,       A_OUT_SZ = 256 * 576;
constexpr int A_OFF_OFF = A_OUT_OFF + A_OUT_SZ,     A_OFF_SZ = 64 * 1152;   // 27 padded to 64
constexpr int A_DCN_OFF = A_OFF_OFF + 4 * A_OFF_SZ, A_DCN_SZ = 64 * 1152;
constexpr int A_TOT = A_DCN_OFF + 4 * A_DCN_SZ;     // 884736 shorts = 1.77 MB

// ---------- wprep_a: x NCHW f32 -> NHWC bf16 (2304 blocks) + A_IN cvt (576 blocks) ----------
constexpr int WPA_X = 2304;                          // N*HW*32 ids
constexpr int WPA_AIN = A_IN_SZ / 256;               // 576
__global__ __launch_bounds__(256) void wprep_a(
        const float* __restrict__ x, const float* __restrict__ w_in,
        u16* __restrict__ xT, u16* __restrict__ dst) {
    if (blockIdx.x < WPA_X) {
        int id = blockIdx.x * 256 + threadIdx.x;
        int c8 = id & 31;
        int pix = id >> 5;
        int n = pix / HW_, p = pix % HW_;
        const float* s = x + ((size_t)n * 256 + c8 * 8) * HW_ + p;
        short8 vv;
#pragma unroll
        for (int j = 0; j < 8; ++j) vv[j] = f2b(s[(size_t)j * HW_]);
        *reinterpret_cast<short8*>(xT + (size_t)pix * 256 + c8 * 8) = vv;
    } else {
        int id = (blockIdx.x - WPA_X) * 256 + threadIdx.x;   // < A_IN_SZ
        int m = id / 2304, k = id % 2304;
        int tap = k >> 8, ic = k & 255;
        short sb = f2b(w_in[m * 2304 + ic * 9 + tap]);
        dst[id] = *reinterpret_cast<u16*>(&sb);
    }
}

// ---------- fat: conv_in (384 blocks, icc-pipelined dbuf) + rest-weight cvt + tpl prep ----------
constexpr int CF_CONV = 384;
constexpr int CF_WREST = (A_TOT - A_IN_SZ) / 256;    // 2880
constexpr int CF_TPL = N_ * HW_ * 8 / 256;           // 576
constexpr int CF_GRID = CF_CONV + CF_WREST + CF_TPL; // 3840

__global__ __launch_bounds__(256) void cin_fat(
        const u16* __restrict__ X, const u16* __restrict__ A,
        const float* __restrict__ bias, float* __restrict__ out,
        u16* __restrict__ ta, u16* __restrict__ tb,
        const float* __restrict__ w_out,
        const float* __restrict__ ow0, const float* __restrict__ ow1,
        const float* __restrict__ ow2, const float* __restrict__ ow3,
        const float* __restrict__ w0, const float* __restrict__ w1,
        const float* __restrict__ w2, const float* __restrict__ w3,
        u16* __restrict__ dst, const float* __restrict__ tpl) {
    __shared__ __align__(16) u16 Xl[2][3][50][72];   // 43200 B double buffer
    int t = threadIdx.x;
    if (blockIdx.x < CF_CONV) {
        // conv_in: IC=256, OC=64, 48-px strips, icc-pipelined
        int bid = blockIdx.x;
        int b = (bid & 7) * 48 + (bid >> 3);         // XCD swizzle within 384
        int n = b / 192, rr = b % 192;
        int y = rr >> 1, px0 = (rr & 1) * 48;
        int w = t >> 6, lane = t & 63, lm = lane & 15, q = lane >> 4;
        const u16* Arow = A + (size_t)(w * 16 + lm) * 2304 + q * 8;
        floatx4 acc[3];
#pragma unroll
        for (int a = 0; a < 3; ++a) acc[a] = {0.f, 0.f, 0.f, 0.f};
        const short8 zz = {0, 0, 0, 0, 0, 0, 0, 0};

        auto stage = [&](int icc, int pb) {
#pragma unroll
            for (int it = 0; it < 5; ++it) {
                int id = it * 256 + t;
                if (id < 1200) {
                    int ch8 = id & 7;
                    int tmp = id >> 3;
                    int pxl = tmp % 50, row = tmp / 50;
                    int xg = px0 - 1 + pxl;
                    int yg = y - 1 + row;
                    bool vld = (yg >= 0) && (yg < 96) && (xg >= 0) && (xg < 96);
                    short8 vv = zz;
                    if (vld)
                        vv = *reinterpret_cast<const short8*>(
                            X + ((size_t)(n * HW_ + yg * 96 + xg)) * 256 + icc * 64 + ch8 * 8);
                    *reinterpret_cast<short8*>(&Xl[pb][row][pxl][ch8 * 8]) = vv;
                }
            }
        };

        stage(0, 0);
        __syncthreads();
#pragma unroll
        for (int icc = 0; icc < 4; ++icc) {
            const int pb = icc & 1;
            if (icc < 3) stage(icc + 1, pb ^ 1);     // overlap next stage with this MFMA
            short8 af[9][2];
#pragma unroll
            for (int tap = 0; tap < 9; ++tap)
#pragma unroll
                for (int ks = 0; ks < 2; ++ks)
                    af[tap][ks] = *reinterpret_cast<const short8*>(Arow + tap * 256 + icc * 64 + ks * 32);
#pragma unroll
            for (int tap = 0; tap < 9; ++tap) {
                int ky = tap / 3, kx = tap % 3;
#pragma unroll
                for (int ks = 0; ks < 2; ++ks)
#pragma unroll
                    for (int nf = 0; nf < 3; ++nf) {
                        short8 bv = *reinterpret_cast<const short8*>(&Xl[pb][ky][nf * 16 + lm + kx][ks * 32 + q * 8]);
                        acc[nf] = __builtin_amdgcn_mfma_f32_16x16x32_bf16(af[tap][ks], bv, acc[nf], 0, 0, 0);
                    }
            }
            __syncthreads();
        }
        int ocb = w * 16 + q * 4;
#pragma unroll
        for (int nf = 0; nf < 3; ++nf) {
            int px = px0 + nf * 16 + lm;
            int pix = n * HW_ + y * 96 + px;
            bh4 bo;
#pragma unroll
            for (int rr2 = 0; rr2 < 4; ++rr2) {
                int oc = ocb + rr2;
                float v = acc[nf][rr2] + bias[oc];
                out[((size_t)(n * 64 + oc)) * HW_ + y * 96 + px] = v;
                bo[rr2] = f2b(v);
            }
            *reinterpret_cast<bh4*>(ta + (size_t)pix * 128 + 64 + ocb) = bo;   // xh -> ta ch 64..127
            *reinterpret_cast<bh4*>(tb + (size_t)pix * 128 + ocb) = bo;        // xh -> tb ch 0..63
        }
    } else if (blockIdx.x < CF_CONV + CF_WREST) {
        // remaining weight conversion: ids A_IN_SZ..A_TOT
        int id = A_IN_SZ + (blockIdx.x - CF_CONV) * 256 + t;
        float v;
        if (id < A_OFF_OFF) {
            int l = id - A_OUT_OFF; int m = l / 576, k = l % 576; int tap = k / 64, ic = k & 63;
            v = w_out[m * 576 + ic * 9 + tap];
        } else if (id < A_DCN_OFF) {
            int l = id - A_OFF_OFF; int i = l / A_OFF_SZ, l2 = l % A_OFF_SZ;
            int m = l2 / 1152, k = l2 % 1152; int tap = k >> 7, ic = k & 127;
            const float* s = (i == 0) ? ow0 : (i == 1) ? ow1 : (i == 2) ? ow2 : ow3;
            v = (m < 27) ? s[m * 1152 + ic * 9 + tap] : 0.f;
        } else {
            int l = id - A_DCN_OFF; int i = l / A_DCN_SZ, l2 = l % A_DCN_SZ;
            int m = l2 / 1152, k = l2 % 1152; int tap = k >> 7, c = k & 127;
            const float* s = (i == 0) ? w0 : (i == 1) ? w1 : (i == 2) ? w2 : w3;
            v = s[m * 1152 + c * 9 + tap];
        }
        short sb = f2b(v);
        dst[id] = *reinterpret_cast<u16*>(&sb);
    } else {
        // tpl -> ta[0:64] / tb[64:128]
        int id2 = (blockIdx.x - CF_CONV - CF_WREST) * 256 + t;
        int c8 = id2 & 7;
        int pix = id2 >> 3;
        int n = pix / HW_, p = pix % HW_;
        const float* s = tpl + ((size_t)n * 64 + c8 * 8) * HW_ + p;
        short8 vv;
#pragma unroll
        for (int j = 0; j < 8; ++j) vv[j] = f2b(s[(size_t)j * HW_]);
        *reinterpret_cast<short8*>(ta + (size_t)pix * 128 + c8 * 8) = vv;
        *reinterpret_cast<short8*>(tb + (size_t)pix * 128 + 64 + c8 * 8) = vv;
    }
}

// ---------- conv_out: R7 48-px implicit GEMM (IC=64, OC=256) ----------
template <int IC, int OCST>
__global__ __launch_bounds__(256) void conv_gemm(const u16* __restrict__ X,
                                                 const u16* __restrict__ A,
                                                 const float* __restrict__ bias,
                                                 float* __restrict__ out) {
    __shared__ __align__(16) u16 Xl[3][50][72];
    int cpx = gridDim.x >> 3;
    int bb = (blockIdx.x & 7) * cpx + (blockIdx.x >> 3);
    int r = bb % 384, mt = bb / 384, t = threadIdx.x;
    constexpr int K = IC * 9;
    constexpr int ICC = IC / 64;
    int n = r / 192;
    int rr = r % 192;
    int y = rr >> 1, px0 = (rr & 1) * 48;
    int w = t >> 6, lane = t & 63, lm = lane & 15, q = lane >> 4;
    const u16* Arow = A + (size_t)(mt * 64 + w * 16 + lm) * K + q * 8;
    floatx4 acc[3];
#pragma unroll
    for (int a = 0; a < 3; ++a) acc[a] = {0.f, 0.f, 0.f, 0.f};
    const short8 zz = {0, 0, 0, 0, 0, 0, 0, 0};

    for (int icc = 0; icc < ICC; ++icc) {
        short8 af[9][2];
#pragma unroll
        for (int tap = 0; tap < 9; ++tap)
#pragma unroll
            for (int ks = 0; ks < 2; ++ks)
                af[tap][ks] = *reinterpret_cast<const short8*>(Arow + tap * IC + icc * 64 + ks * 32);
        __syncthreads();
#pragma unroll
        for (int it = 0; it < 5; ++it) {
            int id = it * 256 + t;
            if (id < 1200) {
                int ch8 = id & 7;
                int tmp = id >> 3;
                int pxl = tmp % 50, row = tmp / 50;
                int xg = px0 - 1 + pxl;
                int yg = y - 1 + row;
                bool vld = (yg >= 0) && (yg < 96) && (xg >= 0) && (xg < 96);
                short8 vv = zz;
                if (vld)
                    vv = *reinterpret_cast<const short8*>(
                        X + ((size_t)(n * HW_ + yg * 96 + xg)) * IC + icc * 64 + ch8 * 8);
                *reinterpret_cast<short8*>(&Xl[row][pxl][ch8 * 8]) = vv;
            }
        }
        __syncthreads();
#pragma unroll
        for (int tap = 0; tap < 9; ++tap) {
            int ky = tap / 3, kx = tap % 3;
#pragma unroll
            for (int ks = 0; ks < 2; ++ks) {
#pragma unroll
                for (int nf = 0; nf < 3; ++nf) {
                    short8 bv = *reinterpret_cast<const short8*>(&Xl[ky][nf * 16 + lm + kx][ks * 32 + q * 8]);
                    acc[nf] = __builtin_amdgcn_mfma_f32_16x16x32_bf16(af[tap][ks], bv, acc[nf], 0, 0, 0);
                }
            }
        }
    }
    int ocb = mt * 64 + w * 16 + q * 4;
#pragma unroll
    for (int nf = 0; nf < 3; ++nf) {
        int px = px0 + nf * 16 + lm;
#pragma unroll
        for (int rr2 = 0; rr2 < 4; ++rr2) {
            int oc = ocb + rr2;
            if (oc < OCST)
                out[((size_t)(n * OCST + oc)) * HW_ + y * 96 + px] = acc[nf][rr2] + bias[oc];
        }
    }
}

// ---------- od body (offset-conv + dcn + optional gate), pool-based LDS (R7 proven) ----------
constexpr int P1XL_B = 21600;
constexpr int P1_B   = 26784;
constexpr int SM_SZ2 = 35424;

template <int GATE>
__device__ __forceinline__ void od_body(char* smem, int b, int t,
        const u16* __restrict__ X0, const u16* __restrict__ X1,
        const u16* __restrict__ Ao0, const u16* __restrict__ Ao1,
        const float* __restrict__ bo0, const float* __restrict__ bo1,
        const u16* __restrict__ Ad0, const u16* __restrict__ Ad1,
        const float* __restrict__ bd0, const float* __restrict__ bd1,
        float* __restrict__ o0, float* __restrict__ o1,
        const float* __restrict__ g0, const float* __restrict__ g1,
        const float* __restrict__ t0, const float* __restrict__ t1,
        u16* __restrict__ xeh, float* __restrict__ ontpl) {
    u16 (*Xl)[50][72] = reinterpret_cast<u16(*)[50][72]>(smem);
    float (*om_l)[48] = reinterpret_cast<float(*)[48]>(smem + P1XL_B);
    u16 (*Bl)[48][136] = reinterpret_cast<u16(*)[48][136]>(smem);
    int* s_y0 = reinterpret_cast<int*>(smem + P1_B);
    int* s_x0 = s_y0 + 432;
    float* s_wy = reinterpret_cast<float*>(s_x0 + 432);
    float* s_wx = s_wy + 432;
    float* s_m  = s_wx + 432;

    int inst = b / 384, r = b % 384;
    const u16* X = inst ? X1 : X0;
    const u16* Ao = inst ? Ao1 : Ao0;
    const float* bo = inst ? bo1 : bo0;
    const u16* Ad = inst ? Ad1 : Ad0;
    const float* bd = inst ? bd1 : bd0;
    int n = r / 192, rr = r % 192;
    int y = rr >> 1, px0 = (rr & 1) * 48;
    int w = t >> 6, lane = t & 63, lm = lane & 15, q = lane >> 4;
    const short8 zz = {0, 0, 0, 0, 0, 0, 0, 0};

    // ---- phase 1: offset conv -> om_l ----
    {
        const u16* Arow = Ao + (size_t)(w * 16 + lm) * 1152 + q * 8;
        floatx4 acc[3];
#pragma unroll
        for (int a = 0; a < 3; ++a) acc[a] = {0.f, 0.f, 0.f, 0.f};
        for (int icc = 0; icc < 2; ++icc) {
            short8 af[9][2];
#pragma unroll
            for (int tap = 0; tap < 9; ++tap)
#pragma unroll
                for (int ks = 0; ks < 2; ++ks)
                    af[tap][ks] = *reinterpret_cast<const short8*>(Arow + tap * 128 + icc * 64 + ks * 32);
            __syncthreads();
#pragma unroll
            for (int it = 0; it < 5; ++it) {
                int id = it * 256 + t;
                if (id < 1200) {
                    int ch8 = id & 7;
                    int tmp = id >> 3;
                    int pxl = tmp % 50, row = tmp / 50;
                    int xg = px0 - 1 + pxl;
                    int yg = y - 1 + row;
                    bool vld = (yg >= 0) && (yg < 96) && (xg >= 0) && (xg < 96);
                    short8 vv = zz;
                    if (vld)
                        vv = *reinterpret_cast<const short8*>(
                            X + ((size_t)(n * HW_ + yg * 96 + xg)) * 128 + icc * 64 + ch8 * 8);
                    *reinterpret_cast<short8*>(&Xl[row][pxl][ch8 * 8]) = vv;
                }
            }
            __syncthreads();
#pragma unroll
            for (int tap = 0; tap < 9; ++tap) {
                int ky = tap / 3, kx = tap % 3;
#pragma unroll
                for (int ks = 0; ks < 2; ++ks) {
#pragma unroll
                    for (int nf = 0; nf < 3; ++nf) {
                        short8 bv = *reinterpret_cast<const short8*>(&Xl[ky][nf * 16 + lm + kx][ks * 32 + q * 8]);
                        acc[nf] = __builtin_amdgcn_mfma_f32_16x16x32_bf16(af[tap][ks], bv, acc[nf], 0, 0, 0);
                    }
                }
            }
        }
        int ocb = w * 16 + q * 4;
#pragma unroll
        for (int nf = 0; nf < 3; ++nf) {
            int xl = nf * 16 + lm;
#pragma unroll
            for (int rr2 = 0; rr2 < 4; ++rr2) {
                int oc = ocb + rr2;
                if (oc < 27) om_l[oc][xl] = acc[nf][rr2] + bo[oc];
            }
        }
    }
    __syncthreads();

    for (int e = t; e < 432; e += 256) {
        int k9 = e / 48, xl = e % 48;
        int x = px0 + xl;
        float dy = om_l[k9][xl];
        float dx = om_l[9 + k9][xl];
        float ml = om_l[18 + k9][xl];
        float py = (float)y + (float)(k9 / 3 - 1) + dy;
        float px = (float)x + (float)(k9 % 3 - 1) + dx;
        float fy = floorf(py), fx = floorf(px);
        s_y0[e] = (int)fy; s_x0[e] = (int)fx;
        s_wy[e] = py - fy; s_wx[e] = px - fx; s_m[e] = sigm(ml);
    }
    __syncthreads();

    // ---- phase 2: dcn, per-tap staging, register-pipelined ----
    const u16* Arow = Ad + (size_t)(w * 16 + lm) * 1152 + q * 8;
    floatx4 acc[3];
#pragma unroll
    for (int a = 0; a < 3; ++a) acc[a] = {0.f, 0.f, 0.f, 0.f};
    const u16* txn = X + (size_t)n * HW_ * 128;
    int p = 0;
    int cg = t & 15, px0i = t >> 4;
    short8 cr[3][4];
    short8 afP[2][2];

    auto issueT = [&](int tap) {
#pragma unroll
        for (int s = 0; s < 3; ++s) {
            int pxi = px0i + s * 16;
            int ce = tap * 48 + pxi;
            int y0 = s_y0[ce], x0c = s_x0[ce];
            bool yv0 = (y0 >= 0) & (y0 < 96), yv1 = (y0 >= -1) & (y0 < 95);
            bool xv0 = (x0c >= 0) & (x0c < 96), xv1 = (x0c >= -1) & (x0c < 95);
            const u16* gb = txn + (long)(y0 * 96 + x0c) * 128 + cg * 8;
            cr[s][0] = (yv0 && xv0) ? *reinterpret_cast<const short8*>(gb) : zz;
            cr[s][1] = (yv0 && xv1) ? *reinterpret_cast<const short8*>(gb + 128) : zz;
            cr[s][2] = (yv1 && xv0) ? *reinterpret_cast<const short8*>(gb + 96 * 128) : zz;
            cr[s][3] = (yv1 && xv1) ? *reinterpret_cast<const short8*>(gb + 96 * 128 + 128) : zz;
        }
    };
    auto computeT = [&](int tap) {
#pragma unroll
        for (int s = 0; s < 3; ++s) {
            int pxi = px0i + s * 16;
            int ce = tap * 48 + pxi;
            float wy = s_wy[ce], wx = s_wx[ce], m = s_m[ce];
            float w00 = (1.f - wy) * (1.f - wx) * m;
            float w01 = (1.f - wy) * wx * m;
            float w10 = wy * (1.f - wx) * m;
            float w11 = wy * wx * m;
            short8 vv;
#pragma unroll
            for (int j = 0; j < 8; ++j) {
                float f = b2f(cr[s][0][j]) * w00 + b2f(cr[s][1][j]) * w01 +
                          b2f(cr[s][2][j]) * w10 + b2f(cr[s][3][j]) * w11;
                vv[j] = f2b(f);
            }
            *reinterpret_cast<short8*>(&Bl[p][pxi][cg * 8]) = vv;
        }
    };

    issueT(0);
    for (int tap = 0; tap < 9; ++tap) {
        if (tap > 0) {
#pragma unroll
            for (int half = 0; half < 2; ++half)
#pragma unroll
                for (int ks = 0; ks < 2; ++ks)
#pragma unroll
                    for (int nf = 0; nf < 3; ++nf) {
                        short8 bv = *reinterpret_cast<const short8*>(
                            &Bl[p ^ 1][nf * 16 + lm][half * 64 + ks * 32 + q * 8]);
                        acc[nf] = __builtin_amdgcn_mfma_f32_16x16x32_bf16(afP[half][ks], bv, acc[nf], 0, 0, 0);
                    }
        }
        computeT(tap);
        if (tap < 8) issueT(tap + 1);
#pragma unroll
        for (int half = 0; half < 2; ++half)
#pragma unroll
            for (int ks = 0; ks < 2; ++ks)
                afP[half][ks] = *reinterpret_cast<const short8*>(Arow + (tap * 2 + half) * 64 + ks * 32);
        __syncthreads();
        p ^= 1;
    }
#pragma unroll
    for (int half = 0; half < 2; ++half)
#pragma unroll
        for (int ks = 0; ks < 2; ++ks)
#pragma unroll
            for (int nf = 0; nf < 3; ++nf) {
                short8 bv = *reinterpret_cast<const short8*>(
                    &Bl[p ^ 1][nf * 16 + lm][half * 64 + ks * 32 + q * 8]);
                acc[nf] = __builtin_amdgcn_mfma_f32_16x16x32_bf16(afP[half][ks], bv, acc[nf], 0, 0, 0);
            }

    int ocb = w * 16 + q * 4;
    if constexpr (GATE == 0) {
        float* out = inst ? o1 : o0;
#pragma unroll
        for (int nf = 0; nf < 3; ++nf) {
            int px = px0 + nf * 16 + lm;
#pragma unroll
            for (int rr2 = 0; rr2 < 4; ++rr2) {
                int oc = ocb + rr2;
                out[((size_t)(n * CH_ + oc)) * HW_ + y * 96 + px] = acc[nf][rr2] + bd[oc];
            }
        }
    } else {
        const float* gz = inst ? g1 : g0;
        const float* tt = inst ? t1 : t0;
#pragma unroll
        for (int nf = 0; nf < 3; ++nf) {
            int px = px0 + nf * 16 + lm;
            if (!inst) {
                bh4 bo4;
#pragma unroll
                for (int rr2 = 0; rr2 < 4; ++rr2) {
                    int oc = ocb + rr2;
                    size_t idx = ((size_t)(n * CH_ + oc)) * HW_ + y * 96 + px;
                    float z = sigm(gz[idx]);
                    float xt = tanhf(acc[nf][rr2] + bd[oc]);
                    bo4[rr2] = f2b((1.f - z) * tt[idx] + z * xt);
                }
                *reinterpret_cast<bh4*>(xeh + ((size_t)(n * HW_ + y * 96 + px)) * 64 + ocb) = bo4;
            } else {
#pragma unroll
                for (int rr2 = 0; rr2 < 4; ++rr2) {
                    int oc = ocb + rr2;
                    size_t idx = ((size_t)(n * CH_ + oc)) * HW_ + y * 96 + px;
                    float z = sigm(gz[idx]);
                    float xt = tanhf(acc[nf][rr2] + bd[oc]);
                    ontpl[idx] = (1.f - z) * tt[idx] + z * xt;
                }
            }
        }
    }
}

// ---------- ncf body, pool-based LDS (33856 B <= SM_SZ2) ----------
__device__ __forceinline__ void ncf_body(char* smem, int b, int t,
        const u16* __restrict__ in0, const u16* __restrict__ in1,
        u16* __restrict__ out0, u16* __restrict__ out1) {
    u16 (*sF2)[28][72] = reinterpret_cast<u16(*)[28][72]>(smem);           // 28224 B
    u16 (*sF1)[72] = reinterpret_cast<u16(*)[72]>(smem + 28224);           // 2304 B
    float (*sc)[52] = reinterpret_cast<float(*)[52]>(smem + 30528);        // 3328 B
    int inst = b / 1152, bb = b % 1152;
    const u16* txh = inst ? in1 : in0;
    u16* txh2 = inst ? out1 : out0;
    int n = bb / 576, rem = bb % 576;
    int y = rem / 6, x0 = (rem % 6) * 16;
    const u16* base = txh + (size_t)n * HW_ * 128;
    const short8 zz = {0, 0, 0, 0, 0, 0, 0, 0};

    for (int id = t; id < 1568; id += 256) {
        int ch8 = id & 7;
        int tmp = id >> 3;
        int px = tmp % 28, row = tmp / 28;
        int yy = y + row * 2 - 6;
        int xg = x0 - 6 + px;
        short8 vv = zz;
        if (yy >= 0 && yy < 96 && xg >= 0 && xg < 96)
            vv = *reinterpret_cast<const short8*>(base + (size_t)(yy * 96 + xg) * 128 + ch8 * 8);
        *reinterpret_cast<short8*>(&sF2[row][px][ch8 * 8]) = vv;
    }
    if (t < 128) {
        int ch8 = t & 7, lp0 = t >> 3;
        short8 vv = *reinterpret_cast<const short8*>(base + (size_t)(y * 96 + x0 + lp0) * 128 + 64 + ch8 * 8);
        *reinterpret_cast<short8*>(&sF1[lp0][ch8 * 8]) = vv;
    }
    __syncthreads();

    int lp = t >> 4, j = t & 15;
    for (int k = j; k < 49; k += 16) {
        int ky = k / 7, kx = k % 7;
        const u16* f2p = &sF2[ky][lp + 2 * kx][0];
        const u16* f1p = &sF1[lp][0];
        float s = 0.f;
#pragma unroll
        for (int c8 = 0; c8 < 8; ++c8) {
            short8 a = *reinterpret_cast<const short8*>(f1p + c8 * 8);
            short8 b2 = *reinterpret_cast<const short8*>(f2p + c8 * 8);
#pragma unroll
            for (int u = 0; u < 8; ++u) s += b2f(a[u]) * b2f(b2[u]);
        }
        sc[lp][k] = s * 0.125f;
    }
    float mx = -1e30f;
    for (int k = j; k < 49; k += 16) mx = fmaxf(mx, sc[lp][k]);
#pragma unroll
    for (int m = 1; m <= 8; m <<= 1) mx = fmaxf(mx, __shfl_xor(mx, m, 64));
    float e[4];
    float sum = 0.f;
    int cnt = 0;
    for (int k = j; k < 49; k += 16) { e[cnt] = __expf(sc[lp][k] - mx); sum += e[cnt]; ++cnt; }
#pragma unroll
    for (int m = 1; m <= 8; m <<= 1) sum += __shfl_xor(sum, m, 64);
    float inv = 1.f / sum;
    cnt = 0;
    for (int k = j; k < 49; k += 16) sc[lp][k] = e[cnt++] * inv;
    __syncthreads();
    int ch0 = j * 4;
    float acc[4];
#pragma unroll
    for (int u = 0; u < 4; ++u) acc[u] = 0.f;
#pragma unroll
    for (int k = 0; k < 49; ++k) {
        int ky = k / 7, kx = k % 7;
        float a = sc[lp][k];
        bh4 f2 = *reinterpret_cast<const bh4*>(&sF2[ky][lp + 2 * kx][ch0]);
#pragma unroll
        for (int u = 0; u < 4; ++u) acc[u] += a * b2f(f2[u]);
    }
    int p = y * 96 + x0 + lp;
    u16* obase = txh2 + (size_t)n * HW_ * 128 + (size_t)p * 128;
    bh4 ro;
#pragma unroll
    for (int u = 0; u < 4; ++u) ro[u] = f2b(acc[u]);
    *reinterpret_cast<bh4*>(obase + ch0) = ro;
    *reinterpret_cast<bh4*>(obase + 64 + ch0) =
        *reinterpret_cast<const bh4*>(&sF1[lp][ch0]);   // tt passthrough
}

// ---------- fat: od<0> (768 blocks) + ncf2 (2304 blocks) co-resident ----------
__global__ __launch_bounds__(256, 4) void od0_ncf(
        const u16* __restrict__ Xa, const u16* __restrict__ Xb,
        const u16* __restrict__ Ao0, const u16* __restrict__ Ao1,
        const float* __restrict__ bo0, const float* __restrict__ bo1,
        const u16* __restrict__ Ad0, const u16* __restrict__ Ad1,
        const float* __restrict__ bd0, const float* __restrict__ bd1,
        float* __restrict__ dz0, float* __restrict__ dz1,
        u16* __restrict__ t2a, u16* __restrict__ t2b) {
    __shared__ __align__(16) char smem[SM_SZ2];
    int t = threadIdx.x;
    if (blockIdx.x < 768) {
        int bid = blockIdx.x;
        int b = (bid & 7) * 96 + (bid >> 3);
        od_body<0>(smem, b, t, Xa, Xb, Ao0, Ao1, bo0, bo1, Ad0, Ad1, bd0, bd1,
                   dz0, dz1, nullptr, nullptr, nullptr, nullptr, nullptr, nullptr);
    } else {
        int bid = blockIdx.x - 768;
        int b = (bid & 7) * 288 + (bid >> 3);
        ncf_body(smem, b, t, Xa, Xb, t2a, t2b);
    }
}

// ---------- standalone od<1> with gate epilogue ----------
__global__ __launch_bounds__(256, 4) void od_gate(
        const u16* __restrict__ Xa, const u16* __restrict__ Xb,
        const u16* __restrict__ Ao0, const u16* __restrict__ Ao1,
        const float* __restrict__ bo0, const float* __restrict__ bo1,
        const u16* __restrict__ Ad0, const u16* __restrict__ Ad1,
        const float* __restrict__ bd0, const float* __restrict__ bd1,
        const float* __restrict__ g0, const float* __restrict__ g1,
        const float* __restrict__ t0, const float* __restrict__ t1,
        u16* __restrict__ xeh, float* __restrict__ ontpl) {
    __shared__ __align__(16) char smem[SM_SZ2];
    int bid = blockIdx.x;
    int b = (bid & 7) * 96 + (bid >> 3);
    od_body<1>(smem, b, threadIdx.x, Xa, Xb, Ao0, Ao1, bo0, bo1, Ad0, Ad1, bd0, bd1,
               nullptr, nullptr, g0, g1, t0, t1, xeh, ontpl);
}

extern "C" void kernel_launch(void* const* d_in, const int* in_sizes, int n_in,
                              void* d_out, int out_size, void* d_ws, size_t ws_size,
                              hipStream_t stream) {
    const float* x     = (const float*)d_in[0];
    const float* tpl   = (const float*)d_in[1];
    const float* w_in  = (const float*)d_in[2];
    const float* b_in  = (const float*)d_in[3];
    const float* w_out = (const float*)d_in[4];
    const float* b_out = (const float*)d_in[5];
    const float *pw[4], *pb[4], *pow_[4], *pob[4];
    for (int i = 0; i < 4; ++i) {           // 0=enh_z 1=enh_h 2=upd_z 3=upd_h
        pw[i]   = (const float*)d_in[6 + 4 * i];
        pb[i]   = (const float*)d_in[7 + 4 * i];
        pow_[i] = (const float*)d_in[8 + 4 * i];
        pob[i]  = (const float*)d_in[9 + 4 * i];
    }
    float* out_main = (float*)d_out;
    float* out_ntpl = out_main + (size_t)N_ * CIN_ * HW_;

    // ---- workspace ----
    u16* Aws = (u16*)d_ws;
    u16* xT     = Aws + A_TOT;                        // (N,96,96,256) bf16
    u16* txh_a  = xT + (size_t)N_ * HW_ * CIN_;       // (N,96,96,128) bf16
    u16* txh_b  = txh_a + (size_t)N_ * HW_ * C2_;
    u16* txh2_a = txh_b + (size_t)N_ * HW_ * C2_;
    u16* txh2_b = txh2_a + (size_t)N_ * HW_ * C2_;
    u16* xeh    = txh2_b + (size_t)N_ * HW_ * C2_;    // (N,96,96,64) bf16
    float* fws = (float*)(xeh + (size_t)N_ * HW_ * CH_);
    size_t off = 0;
    float* xh   = fws + off; off += (size_t)N_ * CH_ * HW_;
    float* dz_a = fws + off; off += (size_t)N_ * CH_ * HW_;
    float* dz_b = fws + off; off += (size_t)N_ * CH_ * HW_;

    // 1. x->xT conversion + A_IN weights (prerequisites of conv_in)
    wprep_a<<<WPA_X + WPA_AIN, 256, 0, stream>>>(x, w_in, xT, Aws);
    // 2. fat: conv_in (pipelined) co-resident with remaining weight cvt + tpl prep
    cin_fat<<<CF_GRID, 256, 0, stream>>>(xT, Aws + A_IN_OFF, b_in, xh, txh_a, txh_b,
        w_out, pow_[0], pow_[1], pow_[2], pow_[3], pw[0], pw[1], pw[2], pw[3], Aws, tpl);
    // 3. od<0> + ncf co-resident
    od0_ncf<<<3072, 256, 0, stream>>>(txh_a, txh_b,
        Aws + A_OFF_OFF + 0 * A_OFF_SZ, Aws + A_OFF_OFF + 2 * A_OFF_SZ, pob[0], pob[2],
        Aws + A_DCN_OFF + 0 * A_DCN_SZ, Aws + A_DCN_OFF + 2 * A_DCN_SZ, pb[0], pb[2],
        dz_a, dz_b, txh2_a, txh2_b);
    // 4. od<1> + GRU gate
    od_gate<<<768, 256, 0, stream>>>(txh2_a, txh2_b,
        Aws + A_OFF_OFF + 1 * A_OFF_SZ, Aws + A_OFF_OFF + 3 * A_OFF_SZ, pob[1], pob[3],
        Aws + A_DCN_OFF + 1 * A_DCN_SZ, Aws + A_DCN_OFF + 3 * A_DCN_SZ, pb[1], pb[3],
        dz_a, dz_b, xh, tpl, xeh, out_ntpl);
    // 5. conv_out
    conv_gemm<CH_, 256><<<1536, 256, 0, stream>>>(xeh, Aws + A_OUT_OFF, b_out, out_main);
}